// Round 10
// baseline (580.912 us; speedup 1.0000x reference)
//
#include <hip/hip_runtime.h>

// ---------------------------------------------------------------------------
// Nystrom attention, fp32. b=2,h=8,n=8192,d=64, m=256 landmarks, conv33.
// Round 17: pinv iteration re-expressed as zn = 3.25zc -3.75(zc y) +1.75(zc y2)
// -0.25(zc y3): 3 launches/iter (y | y2||w1 | u||v-atomicAdd) instead of 4,
// z kept fp32 between iterations (split at stage). 25 -> 19 chain launches.
// Tile body = verified round-15. Non-chain kernels unchanged (571us base).
// ---------------------------------------------------------------------------

#define N_SEQ 8192
#define NBH   16
#define MLAND 256
#define DHEAD 64
#define NSPLIT3 8
#define MM_E  (NBH * MLAND * MLAND)   // 1048576 elements per plane
#define LM_E  (NBH * MLAND * DHEAD)   // 262144

typedef __attribute__((ext_vector_type(8))) short bfrag;
typedef __attribute__((ext_vector_type(8))) _Float16 hfrag;
typedef __attribute__((ext_vector_type(4))) float f32x4;

__device__ __forceinline__ void fma8(float (&o)[8], float p, const float4& a, const float4& b) {
    o[0] += p * a.x; o[1] += p * a.y; o[2] += p * a.z; o[3] += p * a.w;
    o[4] += p * b.x; o[5] += p * b.y; o[6] += p * b.z; o[7] += p * b.w;
}

__device__ __forceinline__ float bf2f(unsigned short h) {
    return __uint_as_float(((unsigned)h) << 16);
}

// truncation hi/lo split (bf16): hi = top 16 bits, lo = bf16(v - hi).
__device__ __forceinline__ void splitbf(float v, unsigned short& h, unsigned short& l) {
    unsigned bits = __float_as_uint(v);
    h = (unsigned short)(bits >> 16);
    float r = v - __uint_as_float(bits & 0xffff0000u);
    l = (unsigned short)(__float_as_uint(r) >> 16);
}

// fp16 hi/lo split: ~22 mantissa bits total. h = rn(v), l = rn(v - h).
__device__ __forceinline__ void splith(float v, unsigned short& h, unsigned short& l) {
    _Float16 hf = (_Float16)v;
    _Float16 lf = (_Float16)(v - (float)hf);
    h = __builtin_bit_cast(unsigned short, hf);
    l = __builtin_bit_cast(unsigned short, lf);
}

// read 16 consecutive floats, write hi/lo ushorts u32-packed (bf16 version)
__device__ __forceinline__ void stage16(const float* __restrict__ src,
                                        unsigned short* dh, unsigned short* dl) {
    unsigned* ph = (unsigned*)dh;
    unsigned* pl = (unsigned*)dl;
    #pragma unroll
    for (int o = 0; o < 16; o += 4) {
        float4 a = *(const float4*)(src + o);
        float vv[4] = {a.x, a.y, a.z, a.w};
        unsigned short h[4], l[4];
        #pragma unroll
        for (int u = 0; u < 4; ++u) splitbf(vv[u], h[u], l[u]);
        ph[o / 2]     = (unsigned)h[0] | ((unsigned)h[1] << 16);
        ph[o / 2 + 1] = (unsigned)h[2] | ((unsigned)h[3] << 16);
        pl[o / 2]     = (unsigned)l[0] | ((unsigned)l[1] << 16);
        pl[o / 2 + 1] = (unsigned)l[2] | ((unsigned)l[3] << 16);
    }
}

// fp16 version of stage16
__device__ __forceinline__ void stageh16(const float* __restrict__ src,
                                         unsigned short* dh, unsigned short* dl) {
    unsigned* ph = (unsigned*)dh;
    unsigned* pl = (unsigned*)dl;
    #pragma unroll
    for (int o = 0; o < 16; o += 4) {
        float4 a = *(const float4*)(src + o);
        float vv[4] = {a.x, a.y, a.z, a.w};
        unsigned short h[4], l[4];
        #pragma unroll
        for (int u = 0; u < 4; ++u) splith(vv[u], h[u], l[u]);
        ph[o / 2]     = (unsigned)h[0] | ((unsigned)h[1] << 16);
        ph[o / 2 + 1] = (unsigned)h[2] | ((unsigned)h[3] << 16);
        pl[o / 2]     = (unsigned)l[0] | ((unsigned)l[1] << 16);
        pl[o / 2 + 1] = (unsigned)l[2] | ((unsigned)l[3] << 16);
    }
}

// ---------------------------------------------------------------------------
// 1) landmark means
// ---------------------------------------------------------------------------
__global__ __launch_bounds__(64) void k_landmarks(
    const float* __restrict__ q, const float* __restrict__ k,
    float* __restrict__ ql, float* __restrict__ kl)
{
    int mi = blockIdx.x & 255;
    int bh = blockIdx.x >> 8;
    const float* src = blockIdx.y ? k : q;
    float*       dst = blockIdx.y ? kl : ql;
    int t = threadIdx.x;
    const float* s = src + ((size_t)bh * N_SEQ + (size_t)mi * 32) * DHEAD;
    float acc = 0.f;
    #pragma unroll
    for (int j = 0; j < 32; ++j) acc += s[j * DHEAD + t];
    dst[((size_t)bh * MLAND + mi) * DHEAD + t] = acc * (1.f / 32.f);
}

// ---------------------------------------------------------------------------
// 2) attn2 = softmax(ql @ kl^T) rowwise -> split bf16 planes (xh|xl)
// ---------------------------------------------------------------------------
__global__ __launch_bounds__(256) void k_sim2_softmax(
    const float* __restrict__ ql, const float* __restrict__ kl,
    unsigned short* __restrict__ xs)
{
    unsigned short* xh = xs;
    unsigned short* xl = xs + MM_E;
    int bh = blockIdx.x >> 8;
    int i  = blockIdx.x & 255;
    int t  = threadIdx.x;
    __shared__ float qrow[DHEAD];
    __shared__ float wred[8];
    if (t < DHEAD) qrow[t] = ql[((size_t)bh * MLAND + i) * DHEAD + t];
    __syncthreads();
    const float* krow = kl + ((size_t)bh * MLAND + t) * DHEAD;
    float s = 0.f;
    #pragma unroll
    for (int kk = 0; kk < DHEAD; kk += 4) {
        float4 k4 = *(const float4*)(krow + kk);
        s += qrow[kk] * k4.x + qrow[kk + 1] * k4.y + qrow[kk + 2] * k4.z + qrow[kk + 3] * k4.w;
    }
    float m = s;
    #pragma unroll
    for (int o = 32; o > 0; o >>= 1) m = fmaxf(m, __shfl_xor(m, o, 64));
    int wave = t >> 6, lane = t & 63;
    if (lane == 0) wred[wave] = m;
    __syncthreads();
    float bm = fmaxf(fmaxf(wred[0], wred[1]), fmaxf(wred[2], wred[3]));
    float e = __expf(s - bm);
    float sum = e;
    #pragma unroll
    for (int o = 32; o > 0; o >>= 1) sum += __shfl_xor(sum, o, 64);
    if (lane == 0) wred[4 + wave] = sum;
    __syncthreads();
    float bs = wred[4] + wred[5] + wred[6] + wred[7];
    float val = e / bs;
    unsigned short h, l;
    splitbf(val, h, l);
    size_t idx = ((size_t)bh * MLAND + i) * MLAND + t;
    xh[idx] = h;
    xl[idx] = l;
}

// ---------------------------------------------------------------------------
// 3a) global max of row-sums and col-sums of attn2 (from planes).
// ---------------------------------------------------------------------------
__global__ __launch_bounds__(256) void k_scale_reduce(
    const unsigned short* __restrict__ xs, float* __restrict__ scl)
{
    const unsigned short* xh = xs;
    const unsigned short* xl = xs + MM_E;
    int bh = blockIdx.y, seg = blockIdx.x;
    int t = threadIdx.x;
    size_t b = (size_t)bh * MLAND * MLAND;
    __shared__ float red[32];
    __shared__ float red2[256];

    {
        int r = seg * 16 + (t >> 4);
        int j0 = (t & 15) * 16;
        float rp = 0.f;
        #pragma unroll
        for (int j = 0; j < 16; ++j) {
            size_t idx = b + (size_t)r * MLAND + j0 + j;
            rp += bf2f(xh[idx]) + bf2f(xl[idx]);
        }
        rp += __shfl_xor(rp, 1, 16);
        rp += __shfl_xor(rp, 2, 16);
        rp += __shfl_xor(rp, 4, 16);
        rp += __shfl_xor(rp, 8, 16);
        if ((t & 15) == 0) red[t >> 4] = rp;
        __syncthreads();
        if (t == 0) {
            float m = red[0];
            #pragma unroll
            for (int i = 1; i < 16; ++i) m = fmaxf(m, red[i]);
            atomicMax((unsigned int*)&scl[0], __float_as_uint(m));
        }
        __syncthreads();
    }
    {
        int c = seg * 16 + (t & 15);
        int i0 = (t >> 4) * 16;
        float cp = 0.f;
        #pragma unroll
        for (int i = 0; i < 16; ++i) {
            size_t idx = b + (size_t)(i0 + i) * MLAND + c;
            cp += bf2f(xh[idx]) + bf2f(xl[idx]);
        }
        red2[t] = cp;
        __syncthreads();
        if (t < 16) {
            float s = 0.f;
            #pragma unroll
            for (int g = 0; g < 16; ++g) s += red2[g * 16 + t];
            red[t] = s;
        }
        __syncthreads();
        if (t == 0) {
            float m = red[0];
            #pragma unroll
            for (int i = 1; i < 16; ++i) m = fmaxf(m, red[i]);
            atomicMax((unsigned int*)&scl[1], __float_as_uint(m));
        }
    }
}

// ---------------------------------------------------------------------------
// 3b) z0 = attn2^T / (scl[0]*scl[1])  (planes -> fp32)
// ---------------------------------------------------------------------------
__global__ __launch_bounds__(256) void k_zinit(
    const unsigned short* __restrict__ xs, float* __restrict__ zf,
    const float* __restrict__ scl)
{
    const unsigned short* xh = xs;
    const unsigned short* xl = xs + MM_E;
    __shared__ float tile[32][33];
    int bh = blockIdx.z;
    int i0 = blockIdx.y * 32, j0 = blockIdx.x * 32;
    int t = threadIdx.x;
    int lx = t & 31, ly = t >> 5;
    size_t b = (size_t)bh * MLAND * MLAND;
    #pragma unroll
    for (int p = 0; p < 4; ++p) {
        size_t idx = b + (size_t)(i0 + ly + 8 * p) * MLAND + j0 + lx;
        tile[ly + 8 * p][lx] = bf2f(xh[idx]) + bf2f(xl[idx]);
    }
    __syncthreads();
    float inv = 1.0f / (scl[0] * scl[1]);
    #pragma unroll
    for (int p = 0; p < 4; ++p) {
        float val = tile[lx][ly + 8 * p] * inv;
        size_t idx = b + (size_t)(j0 + ly + 8 * p) * MLAND + i0 + lx;
        zf[idx] = val;
    }
}

// ---------------------------------------------------------------------------
// 4) shared 32x64 GEMM tile (round-15-verified body). A/B from planes or
//    fp32 (split at stage). K=256, N param. Pure product (no diag/scale).
// ---------------------------------------------------------------------------
__device__ __forceinline__ void gemm_tile(
    unsigned short* sm,
    const unsigned short* __restrict__ Ahp, const unsigned short* __restrict__ Alp,
    const float* __restrict__ Afp,
    const unsigned short* __restrict__ Bhp, const unsigned short* __restrict__ Blp,
    const float* __restrict__ Bfp,
    int N, int bh, int m0, int n0, int t, f32x4* acc)
{
    unsigned short* Ah = sm;
    unsigned short* Al = sm + 32 * 72;
    unsigned short* Bh = sm + 2 * 32 * 72;
    unsigned short* Bl = sm + 2 * 32 * 72 + 64 * 72;

    const size_t abase = (size_t)bh * 65536;
    const size_t bbase = (size_t)bh * 256 * N;
    int wave = t >> 6, lane = t & 63;
    int l15 = lane & 15, quad = lane >> 4;
    int wr = wave >> 1, wc = wave & 1;

    for (int kc = 0; kc < 256; kc += 64) {
        __syncthreads();
        {   // stage A rows natural [m][k], 32 rows: thread row m=t&31, 8 k's
            int m = t & 31, ks = (t >> 5) * 8;
            if (Afp) {
                const float* src = Afp + abase + (size_t)(m0 + m) * 256 + kc + ks;
                uint4 hv, lv;
                float4 a0 = *(const float4*)(src);
                float4 a1 = *(const float4*)(src + 4);
                unsigned short h[8], l[8];
                float vv[8] = {a0.x, a0.y, a0.z, a0.w, a1.x, a1.y, a1.z, a1.w};
                #pragma unroll
                for (int u = 0; u < 8; ++u) splitbf(vv[u], h[u], l[u]);
                hv.x = (unsigned)h[0] | ((unsigned)h[1] << 16);
                hv.y = (unsigned)h[2] | ((unsigned)h[3] << 16);
                hv.z = (unsigned)h[4] | ((unsigned)h[5] << 16);
                hv.w = (unsigned)h[6] | ((unsigned)h[7] << 16);
                lv.x = (unsigned)l[0] | ((unsigned)l[1] << 16);
                lv.y = (unsigned)l[2] | ((unsigned)l[3] << 16);
                lv.z = (unsigned)l[4] | ((unsigned)l[5] << 16);
                lv.w = (unsigned)l[6] | ((unsigned)l[7] << 16);
                *(uint4*)&Ah[m * 72 + ks] = hv;
                *(uint4*)&Al[m * 72 + ks] = lv;
            } else {
                size_t off = abase + (size_t)(m0 + m) * 256 + kc + ks;
                *(uint4*)&Ah[m * 72 + ks] = *(const uint4*)&Ahp[off];
                *(uint4*)&Al[m * 72 + ks] = *(const uint4*)&Alp[off];
            }
        }
        {   // stage B transposed [n][k]: thread k=t&63, 16 n's
            int kk = t & 63, ns = (t >> 6) * 16;
            if (Bfp) {
                const float* src = Bfp + bbase + (size_t)(kc + kk) * N + n0 + ns;
                #pragma unroll
                for (int o = 0; o < 16; o += 4) {
                    float4 a = *(const float4*)(src + o);
                    float vv[4] = {a.x, a.y, a.z, a.w};
                    #pragma unroll
                    for (int u = 0; u < 4; ++u) {
                        unsigned short h, l;
                        splitbf(vv[u], h, l);
                        Bh[(ns + o + u) * 72 + kk] = h;
                        Bl[(ns + o + u) * 72 + kk] = l;
                    }
                }
            } else {
                size_t off = bbase + (size_t)(kc + kk) * N + n0 + ns;
                unsigned short hb[16], lb[16];
                *(uint4*)&hb[0] = *(const uint4*)&Bhp[off];
                *(uint4*)&hb[8] = *(const uint4*)&Bhp[off + 8];
                *(uint4*)&lb[0] = *(const uint4*)&Blp[off];
                *(uint4*)&lb[8] = *(const uint4*)&Blp[off + 8];
                #pragma unroll
                for (int u = 0; u < 16; ++u) {
                    Bh[(ns + u) * 72 + kk] = hb[u];
                    Bl[(ns + u) * 72 + kk] = lb[u];
                }
            }
        }
        __syncthreads();

        #pragma unroll
        for (int k0 = 0; k0 < 64; k0 += 32) {
            int kf = k0 + quad * 8;
            int am = wr * 16 + l15;
            bfrag ah = *(const bfrag*)&Ah[am * 72 + kf];
            bfrag al = *(const bfrag*)&Al[am * 72 + kf];
            #pragma unroll
            for (int j = 0; j < 2; ++j) {
                int bn = wc * 32 + j * 16 + l15;
                bfrag bhf = *(const bfrag*)&Bh[bn * 72 + kf];
                bfrag blf = *(const bfrag*)&Bl[bn * 72 + kf];
                acc[j] = __builtin_amdgcn_mfma_f32_16x16x32_bf16(al, bhf, acc[j], 0, 0, 0);
                acc[j] = __builtin_amdgcn_mfma_f32_16x16x32_bf16(ah, blf, acc[j], 0, 0, 0);
                acc[j] = __builtin_amdgcn_mfma_f32_16x16x32_bf16(ah, bhf, acc[j], 0, 0, 0);
            }
        }
    }
}

// L1: y = x @ zc (A planes, B fp32). grid 512, bh-pinned XCD swizzle.
__global__ __launch_bounds__(256) void k_gemm_y(
    const unsigned short* __restrict__ xh, const unsigned short* __restrict__ xl,
    const float* __restrict__ zcf,
    unsigned short* __restrict__ yh, unsigned short* __restrict__ yl)
{
    __shared__ __align__(16) unsigned short sm[13824];
    int bid = blockIdx.x;
    int xcd = bid & 7, slot = bid >> 3;
    int bh = xcd + 8 * (slot & 1);
    int tile = slot >> 1;
    int m0 = (tile >> 2) * 32, n0 = (tile & 3) * 64;
    int t = threadIdx.x;
    f32x4 acc[2] = {};
    gemm_tile(sm, xh, xl, nullptr, nullptr, nullptr, zcf, 256, bh, m0, n0, t, acc);

    int wave = t >> 6, lane = t & 63, l15 = lane & 15, quad = lane >> 4;
    int wr = wave >> 1, wc = wave & 1;
    size_t cb = (size_t)bh * 65536;
    #pragma unroll
    for (int j = 0; j < 2; ++j)
        #pragma unroll
        for (int r = 0; r < 4; ++r) {
            int row = m0 + wr * 16 + quad * 4 + r;
            int col = n0 + wc * 32 + j * 16 + l15;
            unsigned short h, l;
            splitbf(acc[j][r], h, l);
            size_t idx = cb + (size_t)row * 256 + col;
            yh[idx] = h;
            yl[idx] = l;
        }
}

// L2 (grid 1024): role0: y2 = y@y -> planes. role1: w1 = zc@y -> planes,
// plus zn0 = 3.25*zc - 3.75*w1 (fp32 overwrite).
__global__ __launch_bounds__(256) void k_gemm_l2(
    const unsigned short* __restrict__ yh, const unsigned short* __restrict__ yl,
    const float* __restrict__ zcf,
    unsigned short* __restrict__ y2h, unsigned short* __restrict__ y2l,
    unsigned short* __restrict__ w1h, unsigned short* __restrict__ w1l,
    float* __restrict__ znf)
{
    __shared__ __align__(16) unsigned short sm[13824];
    int bid = blockIdx.x;
    int xcd = bid & 7, s = bid >> 3;
    int role = s & 1, s2 = s >> 1;
    int bh = xcd + 8 * (s2 & 1);
    int tile = s2 >> 1;
    int m0 = (tile >> 2) * 32, n0 = (tile & 3) * 64;
    int t = threadIdx.x;
    f32x4 acc[2] = {};

    int wave = t >> 6, lane = t & 63, l15 = lane & 15, quad = lane >> 4;
    int wr = wave >> 1, wc = wave & 1;
    size_t cb = (size_t)bh * 65536;

    if (role == 0) {
        gemm_tile(sm, yh, yl, nullptr, yh, yl, nullptr, 256, bh, m0, n0, t, acc);
        #pragma unroll
        for (int j = 0; j < 2; ++j)
            #pragma unroll
            for (int r = 0; r < 4; ++r) {
                int row = m0 + wr * 16 + quad * 4 + r;
                int col = n0 + wc * 32 + j * 16 + l15;
                unsigned short h, l;
                splitbf(acc[j][r], h, l);
                size_t idx = cb + (size_t)row * 256 + col;
                y2h[idx] = h;
                y2l[idx] = l;
            }
    } else {
        gemm_tile(sm, nullptr, nullptr, zcf, yh, yl, nullptr, 256, bh, m0, n0, t, acc);
        #pragma unroll
        for (int j = 0; j < 2; ++j)
            #pragma unroll
            for (int r = 0; r < 4; ++r) {
                int row = m0 + wr * 16 + quad * 4 + r;
                int col = n0 + wc * 32 + j * 16 + l15;
                float w1v = acc[j][r];
                unsigned short h, l;
                splitbf(w1v, h, l);
                size_t idx = cb + (size_t)row * 256 + col;
                w1h[idx] = h;
                w1l[idx] = l;
                znf[idx] = 3.25f * zcf[idx] - 3.75f * w1v;
            }
    }
}

// L3 (grid 1024): role0: u = zc@y2 -> zn += 1.75u. role1: v = w1@y2 -> zn -= 0.25v.
__global__ __launch_bounds__(256) void k_gemm_l3(
    const float* __restrict__ zcf,
    const unsigned short* __restrict__ y2h, const unsigned short* __restrict__ y2l,
    const unsigned short* __restrict__ w1h, const unsigned short* __restrict__ w1l,
    float* __restrict__ znf)
{
    __shared__ __align__(16) unsigned short sm[13824];
    int bid = blockIdx.x;
    int xcd = bid & 7, s = bid >> 3;
    int role = s & 1, s2 = s >> 1;
    int bh = xcd + 8 * (s2 & 1);
    int tile = s2 >> 1;
    int m0 = (tile >> 2) * 32, n0 = (tile & 3) * 64;
    int t = threadIdx.x;
    f32x4 acc[2] = {};

    int wave = t >> 6, lane = t & 63, l15 = lane & 15, quad = lane >> 4;
    int wr = wave >> 1, wc = wave & 1;
    size_t cb = (size_t)bh * 65536;

    if (role == 0) {
        gemm_tile(sm, nullptr, nullptr, zcf, y2h, y2l, nullptr, 256, bh, m0, n0, t, acc);
        #pragma unroll
        for (int j = 0; j < 2; ++j)
            #pragma unroll
            for (int r = 0; r < 4; ++r) {
                int row = m0 + wr * 16 + quad * 4 + r;
                int col = n0 + wc * 32 + j * 16 + l15;
                atomicAdd(&znf[cb + (size_t)row * 256 + col], 1.75f * acc[j][r]);
            }
    } else {
        gemm_tile(sm, w1h, w1l, nullptr, y2h, y2l, nullptr, 256, bh, m0, n0, t, acc);
        #pragma unroll
        for (int j = 0; j < 2; ++j)
            #pragma unroll
            for (int r = 0; r < 4; ++r) {
                int row = m0 + wr * 16 + quad * 4 + r;
                int col = n0 + wc * 32 + j * 16 + l15;
                atomicAdd(&znf[cb + (size_t)row * 256 + col], -0.25f * acc[j][r]);
            }
    }
}

// W = zfinal @ kv (A fp32, B planes, N=64, fp32 out). grid 128.
__global__ __launch_bounds__(256) void k_gemm_w(
    const float* __restrict__ zf,
    const unsigned short* __restrict__ kvh, const unsigned short* __restrict__ kvl,
    float* __restrict__ W)
{
    __shared__ __align__(16) unsigned short sm[13824];
    int bid = blockIdx.x;
    int xcd = bid & 7, slot = bid >> 3;
    int bh = xcd + 8 * (slot & 1);
    int tile = slot >> 1;
    int m0 = tile * 32, n0 = 0;
    int t = threadIdx.x;
    f32x4 acc[2] = {};
    gemm_tile(sm, nullptr, nullptr, zf, kvh, kvl, nullptr, 64, bh, m0, n0, t, acc);

    int wave = t >> 6, lane = t & 63, l15 = lane & 15, quad = lane >> 4;
    int wr = wave >> 1, wc = wave & 1;
    size_t cb = (size_t)bh * 256 * 64;
    #pragma unroll
    for (int j = 0; j < 2; ++j)
        #pragma unroll
        for (int r = 0; r < 4; ++r) {
            int row = m0 + wr * 16 + quad * 4 + r;
            int col = wc * 32 + j * 16 + l15;
            W[cb + (size_t)row * 64 + col] = acc[j][r];
        }
}

// ---------------------------------------------------------------------------
// 5a) attn3 flash partial, MFMA bf16 hi/lo split. (round 8, unchanged)
// ---------------------------------------------------------------------------
__global__ __launch_bounds__(256, 2) void k_attn3_partial(
    const float* __restrict__ ql, const float* __restrict__ k,
    const float* __restrict__ v, float* __restrict__ pO,
    float* __restrict__ pm, float* __restrict__ pl)
{
    __shared__ __align__(16) unsigned short sm3[36864];
    unsigned short* QH = sm3;
    unsigned short* QL = sm3 + 4608;
    unsigned short* KH = sm3 + 9216;
    unsigned short* KL = sm3 + 13824;
    unsigned short* VH = sm3 + 18432;
    unsigned short* VL = sm3 + 23040;
    unsigned short* PH = sm3 + 27648;
    unsigned short* PL = sm3 + 32256;

    int sp = blockIdx.x;              // 0..7, 1024 keys each
    int m0 = blockIdx.y * 64;         // landmark rows
    int bh = blockIdx.z;
    int t = threadIdx.x;
    int wave = t >> 6, lane = t & 63;
    int l15 = lane & 15, quad = lane >> 4;

    {   // stage Q once: 64 rows x 64 d, natural [m][d]
        int row = t & 63, ds = (t >> 6) * 16;
        const float* src = ql + ((size_t)bh * MLAND + m0 + row) * DHEAD + ds;
        stage16(src, &QH[row * 72 + ds], &QL[row * 72 + ds]);
    }
    __syncthreads();

    bfrag aqh[2], aql[2];
    #pragma unroll
    for (int ks = 0; ks < 2; ++ks) {
        aqh[ks] = *(const bfrag*)&QH[(wave * 16 + l15) * 72 + ks * 32 + quad * 8];
        aql[ks] = *(const bfrag*)&QL[(wave * 16 + l15) * 72 + ks * 32 + quad * 8];
    }

    f32x4 O[4] = {};                  // d-tile ni; lane holds rows quad*4+r
    float M[4], L[4];
    #pragma unroll
    for (int r = 0; r < 4; ++r) { M[r] = -1e30f; L[r] = 0.f; }

    const float* kb = k + (size_t)bh * N_SEQ * DHEAD;
    const float* vb = v + (size_t)bh * N_SEQ * DHEAD;

    for (int cc = 0; cc < 16; ++cc) {
        int c0 = sp * 1024 + cc * 64;
        __syncthreads();              // prev chunk's K/V reads done
        {   // K natural [key][d]
            int key = t & 63, ds = (t >> 6) * 16;
            stage16(kb + (size_t)(c0 + key) * DHEAD + ds,
                    &KH[key * 72 + ds], &KL[key * 72 + ds]);
        }
        {   // V transposed [d][key]
            int key = t & 63, dq = (t >> 6) * 16;
            const float* src = vb + (size_t)(c0 + key) * DHEAD + dq;
            #pragma unroll
            for (int o = 0; o < 16; o += 4) {
                float4 a = *(const float4*)(src + o);
                float vv[4] = {a.x, a.y, a.z, a.w};
                #pragma unroll
                for (int u = 0; u < 4; ++u) {
                    unsigned short h, l;
                    splitbf(vv[u], h, l);
                    VH[(dq + o + u) * 72 + key] = h;
                    VL[(dq + o + u) * 72 + key] = l;
                }
            }
        }
        __syncthreads();

        // --- QK^T ---
        f32x4 S4[4] = {};
        __builtin_amdgcn_s_setprio(1);
        #pragma unroll
        for (int ks = 0; ks < 2; ++ks) {
            #pragma unroll
            for (int ni = 0; ni < 4; ++ni) {
                bfrag bkh = *(const bfrag*)&KH[(ni * 16 + l15) * 72 + ks * 32 + quad * 8];
                bfrag bkl = *(const bfrag*)&KL[(ni * 16 + l15) * 72 + ks * 32 + quad * 8];
                S4[ni] = __builtin_amdgcn_mfma_f32_16x16x32_bf16(aql[ks], bkh, S4[ni], 0, 0, 0);
                S4[ni] = __builtin_amdgcn_mfma_f32_16x16x32_bf16(aqh[ks], bkl, S4[ni], 0, 0, 0);
                S4[ni] = __builtin_amdgcn_mfma_f32_16x16x32_bf16(aqh[ks], bkh, S4[ni], 0, 0, 0);
            }
        }
        __builtin_amdgcn_s_setprio(0);

        // --- online softmax ---
        #pragma unroll
        for (int r = 0; r < 4; ++r) {
            float mv = fmaxf(fmaxf(S4[0][r], S4[1][r]), fmaxf(S4[2][r], S4[3][r]));
            mv = fmaxf(mv, __shfl_xor(mv, 1, 16));
            mv = fmaxf(mv, __shfl_xor(mv, 2, 16));
            mv = fmaxf(mv, __shfl_xor(mv, 4, 16));
            mv = fmaxf(mv, __shfl_xor(mv, 8, 16));
            float nM = fmaxf(M[r], mv);
            float alpha = __expf(M[r] - nM);
            M[r] = nM;
            float rs = 0.f;
            #pragma unroll
            for (int ni = 0; ni < 4; ++ni) {
                float p = __expf(S4[ni][r] - nM);
                S4[ni][r] = p;
                rs += p;
            }
            rs += __shfl_xor(rs, 1, 16);
            rs += __shfl_xor(rs, 2, 16);
            rs += __shfl_xor(rs, 4, 16);
            rs += __shfl_xor(rs, 8, 16);
            L[r] = L[r] * alpha + rs;
            #pragma unroll
            for (int ni = 0; ni < 4; ++ni) O[ni][r] *= alpha;
        }

        // --- P -> LDS hi/lo (same-wave region) ---
        #pragma unroll
        for (int ni = 0; ni < 4; ++ni) {
            #pragma unroll
            for (int r = 0; r < 4; ++r) {
                int row = wave * 16 + quad * 4 + r;
                int col = ni * 16 + l15;
                unsigned short h, l;
                splitbf(S4[ni][r], h, l);
                PH[row * 72 + col] = h;
                PL[row * 72 + col] = l;
            }
        }

        // --- PV ---
        __builtin_amdgcn_s_setprio(1);
        #pragma unroll
        for (int ks = 0; ks < 2; ++ks) {
            bfrag aph = *(const bfrag*)&PH[(wave * 16 + l15) * 72 + ks * 32 + quad * 8];
            bfrag apl = *(const bfrag*)&PL[(wave * 16 + l15) * 72 + ks * 32 + quad * 8];
            #pragma unroll
            for (int ni = 0; ni < 4; ++ni) {
                bfrag bvh = *(const bfrag*)&VH[(ni * 16 + l15) * 72 + ks * 32 + quad * 8];
                bfrag bvl = *(const bfrag*)&VL[(ni * 16 + l15) * 72 + ks * 32 + quad * 8];
                O[ni] = __builtin_amdgcn_mfma_f32_16x16x32_bf16(apl, bvh, O[ni], 0, 0, 0);
                O[ni] = __builtin_amdgcn_mfma_f32_16x16x32_bf16(aph, bvl, O[ni], 0, 0, 0);
                O[ni] = __builtin_amdgcn_mfma_f32_16x16x32_bf16(aph, bvh, O[ni], 0, 0, 0);
            }
        }
        __builtin_amdgcn_s_setprio(0);
    }

    int base = (bh * NSPLIT3 + sp) * MLAND + m0;
    #pragma unroll
    for (int r = 0; r < 4; ++r) {
        int row = wave * 16 + quad * 4 + r;
        if (l15 == 0) { pm[base + row] = M[r]; pl[base + row] = L[r]; }
        #pragma unroll
        for (int ni = 0; ni < 4; ++ni)
            pO[(size_t)(base + row) * DHEAD + ni * 16 + l15] = O[ni][r];
    }
}

// ---------------------------------------------------------------------------
// 5b) combine 8 splits -> kv planes (split bf16)
// ---------------------------------------------------------------------------
__global__ __launch_bounds__(64) void k_attn3_combine(
    const float* __restrict__ pO, const float* __restrict__ pm,
    const float* __restrict__ pl, unsigned short* __restrict__ kvs)
{
    unsigned short* kvh = kvs;
    unsigned short* kvl = kvs + LM_E;
    int bh = blockIdx.x >> 8;
    int m  = blockIdx.x & 255;
    int d  = threadIdx.x;
    float M = -1e30f;
    #pragma unroll
    for (int s = 0; s < NSPLIT3; ++s) M = fmaxf(M, pm[(bh * NSPLIT3 + s) * MLAND + m]);
    float L = 0.f, O = 0.f;
    #pragma unroll
    for (int s = 0; s < NSPLIT3; ++s) {
        int base = (bh * NSPLIT3 + s) * MLAND + m;
        float w = __expf(pm[base] - M);
        L += pl[base] * w;
        O += w * pO[(size_t)base * DHEAD + d];
    }
    float val = O / L;
    unsigned short h, l;
    splitbf(val, h, l);
    size_t idx = ((size_t)bh * MLAND + m) * DHEAD + d;
    kvh[idx] = h;
    kvl[idx] = l;
}

// ---------------------------------------------------------------------------
// 6) out = softmax(q @ kl^T) @ W, MFMA fp16 hi/lo split. (round 11, unchanged)
// ---------------------------------------------------------------------------
__global__ __launch_bounds__(256, 2) void k_attn1_mfma(
    const float* __restrict__ q, const float* __restrict__ kl,
    const float* __restrict__ W, float* __restrict__ out)
{
    __shared__ __align__(16) unsigned short sm1[36864];
    unsigned short* QH = sm1;
    unsigned short* QL = sm1 + 4608;
    unsigned short* KH = sm1 + 9216;
    unsigned short* KL = sm1 + 13824;
    unsigned short* WH = sm1 + 18432;
    unsigned short* WL = sm1 + 23040;
    unsigned short* PH = sm1 + 27648;
    unsigned short* PL = sm1 + 32256;

    int bh = blockIdx.y;
    int r0 = blockIdx.x * 64;
    int t = threadIdx.x;
    int wave = t >> 6, lane = t & 63;
    int l15 = lane & 15, quad = lane >> 4;

    {   // stage Q once: 64 rows x 64 d, natural [m][d], fp16 hi/lo
        int row = t & 63, ds = (t >> 6) * 16;
        const float* src = q + ((size_t)bh * N_SEQ + r0 + row) * DHEAD + ds;
        stageh16(src, &QH[row * 72 + ds], &QL[row * 72 + ds]);
    }
    __syncthreads();

    hfrag aqh[2], aql[2];
    #pragma unroll
    for (int ks = 0; ks < 2; ++ks) {
        aqh[ks] = *(const hfrag*)&QH[(wave * 16 + l15) * 72 + ks * 32 + quad * 8];
        aql[ks] = *(const hfrag*)&QL[(wave * 16 + l15) * 72 + ks * 32 + quad * 8];
    }

    f32x4 O4[4] = {};                 // d-tile ni; lane holds rows quad*4+r
    float M[4], L[4];
    #pragma unroll
    for (int r = 0; r < 4; ++r) { M[r] = -1e30f; L[r] = 0.f; }

    for (int mc = 0; mc < 4; ++mc) {
        __syncthreads();              // prev chunk's KL/W reads done
        {   // kl chunk natural [land][d], fp16 hi/lo
            int key = t & 63, ds = (t >> 6) * 16;
            stageh16(kl + ((size_t)bh * MLAND + mc * 64 + key) * DHEAD + ds,
                     &KH[key * 72 + ds], &KL[key * 72 + ds]);
        }
        {   // W chunk transposed [d][land], scaled 1/64, fp16 hi/lo
            int key = t & 63, dq = (t >> 6) * 16;
            const float* src = W + ((size_t)bh * MLAND + mc * 64 + key) * DHEAD + dq;
            #pragma unroll
            for (int o = 0; o < 16; o += 4) {
                float4 a = *(const float4*)(src + o);
                float vv[4] = {a.x * 0.015625f, a.y * 0.015625f,
                               a.z * 0.015625f, a.w * 0.015625f};
                #pragma unroll
                for (int u = 0; u < 4; ++u) {
                    unsigned short h, l;
                    splith(vv[u], h, l);
                    WH[(dq + o + u) * 72 + key] = h;
                    WL[(dq + o + u) * 72 + key] = l;
                }
            }
        }
        __syncthreads();

        // --- q @ kl^T (fp16 hi/lo, 3 products) ---
        f32x4 S4[4] = {};
        __builtin_amdgcn_s_setprio(1);
        #pragma unroll
        for (int ks = 0; ks < 2; ++ks) {
            #pragma unroll
            for (int ni = 0; ni < 4; ++ni) {
                hfrag bkh = *(const hfrag*)&KH[(ni * 16 + l15) * 72 + ks * 32 + quad * 8];
                hfrag bkl = *(const hfrag*)&KL[(ni * 16 + l15) * 72 + ks * 32 + quad * 8];
                S4[ni] = __builtin_amdgcn_mfma_f32_16x16x32_f16(aql[ks], bkh, S4[ni], 0, 0, 0);
                S4[ni] = __builtin_amdgcn_mfma_f32_16x16x32_f16(aqh[ks], bkl, S4[ni], 0, 0, 0);
                S4[ni] = __builtin_amdgcn_mfma_f32_16x16x32_f16(aqh[ks], bkh, S4[ni], 0, 0, 0);
            }
        }
        __builtin_amdgcn_s_setprio(0);

        // --- online softmax (16-lane row groups) ---
        #pragma unroll
        for (int r = 0; r < 4; ++r) {
            float mv = fmaxf(fmaxf(S4[0][r], S4[1][r]), fmaxf(S4[2][r], S4[3][r]));
            mv = fmaxf(mv, __shfl_xor(mv, 1, 16));
            mv = fmaxf(mv, __shfl_xor(mv, 2, 16));
            mv = fmaxf(mv, __shfl_xor(mv, 4, 16));
            mv = fmaxf(mv, __shfl_xor(mv, 8, 16));
            float nM = fmaxf(M[r], mv);
            float alpha = __expf(M[r] - nM);
            M[r] = nM;
            float rs = 0.f;
            #pragma unroll
            for (int ni = 0; ni < 4; ++ni) {
                float p = __expf(S4[ni][r] - nM);
                S4[ni][r] = p;
                rs += p;
            }
            rs += __shfl_xor(rs, 1, 16);
            rs += __shfl_xor(rs, 2, 16);
            rs += __shfl_xor(rs, 4, 16);
            rs += __shfl_xor(rs, 8, 16);
            L[r] = L[r] * alpha + rs;
            #pragma unroll
            for (int ni = 0; ni < 4; ++ni) O4[ni][r] *= alpha;
        }

        // --- P -> LDS fp16 hi/lo (same-wave region) ---
        #pragma unroll
        for (int ni = 0; ni < 4; ++ni) {
            #pragma unroll
            for (int r = 0; r < 4; ++r) {
                int row = wave * 16 + quad * 4 + r;
                int col = ni * 16 + l15;
                unsigned short h, l;
                splith(S4[ni][r], h, l);
                PH[row * 72 + col] = h;
                PL[row * 72 + col] = l;
            }
        }

        // --- P @ W (fp16 hi/lo, 3 products) ---
        __builtin_amdgcn_s_setprio(1);
        #pragma unroll
        for (int ks = 0; ks < 2; ++ks) {
            hfrag aph = *(const hfrag*)&PH[(wave * 16 + l15) * 72 + ks * 32 + quad * 8];
            hfrag apl = *(const hfrag*)&PL[(wave * 16 + l15) * 72 + ks * 32 + quad * 8];
            #pragma unroll
            for (int ni = 0; ni < 4; ++ni) {
                hfrag bwh = *(const hfrag*)&WH[(ni * 16 + l15) * 72 + ks * 32 + quad * 8];
                hfrag bwl = *(const hfrag*)&WL[(ni * 16 + l15) * 72 + ks * 32 + quad * 8];
                O4[ni] = __builtin_amdgcn_mfma_f32_16x16x32_f16(apl, bwh, O4[ni], 0, 0, 0);
                O4[ni] = __builtin_amdgcn_mfma_f32_16x16x32_f16(aph, bwl, O4[ni], 0, 0, 0);
                O4[ni] = __builtin_amdgcn_mfma_f32_16x16x32_f16(aph, bwh, O4[ni], 0, 0, 0);
            }
        }
        __builtin_amdgcn_s_setprio(0);
    }

    // direct store: out[row][d] = O * (64/L)
    float inv[4];
    #pragma unroll
    for (int r = 0; r < 4; ++r) inv[r] = 64.0f / L[r];
    #pragma unroll
    for (int r = 0; r < 4; ++r) {
        int row = wave * 16 + quad * 4 + r;
        float* dst = out + ((size_t)bh * N_SEQ + r0 + row) * DHEAD;
        #pragma unroll
        for (int ni = 0; ni < 4; ++ni)
            dst[ni * 16 + l15] = O4[ni][r] * inv[r];
    }
}

// ---------------------------------------------------------------------------
// 7) out += conv33(v). (round 7-verified, unchanged)
// ---------------------------------------------------------------------------
__global__ __launch_bounds__(256) void k_conv_add(
    const float* __restrict__ v, const float* __restrict__ cw,
    float* __restrict__ out)
{
    __shared__ __align__(16) float smem[160 * 68];
    __shared__ float wgt[33];
    int bh = blockIdx.y;
    int r0 = blockIdx.x * 128;
    int t = threadIdx.x;
    int wave = t >> 6, lane = t & 63;
    int ly = lane >> 3, lx = lane & 7;
    int rb = wave * 32 + ly * 4;

    if (t < 33) wgt[t] = cw[(bh & 7) * 33 + t];

    for (int rr = t; rr < 160; rr += 256) {
        int gr = r0 - 16 + rr;
        bool ok = (gr >= 0) && (gr < N_SEQ);
        const float* src = v + ((size_t)bh * N_SEQ + gr) * DHEAD;
        #pragma unroll
        for (int c = 0; c < 64; c += 4) {
            float4 val = ok ? *(const float4*)(src + c) : make_float4(0.f, 0.f, 0.f, 0.f);
            *(float4*)&smem[rr * 68 + c] = val;
        }
    }
    __syncthreads();

    float res[4][8] = {};
    #pragma unroll
    for (int w = 0; w < 36; ++w) {
        float4 va  = *(const float4*)&smem[(rb + w) * 68 + lx * 8];
        float4 vb4 = *(const float4*)&smem[(rb + w) * 68 + lx * 8 + 4];
        #pragma unroll
        for (int i = 0; i < 4; ++i) {
            if (w - i >= 0 && w - i <= 32) {
                float wv = wgt[w - i];
                fma8(res[i], wv, va, vb4);
            }
        }
    }

    #pragma unroll
    for (int i = 0; i < 4; ++i) {
        float* dst = out + ((size_t)bh * N_SEQ + r0 + rb + i) * DHEAD + lx * 8;
        float4 o0 = *(const float4*)dst;
        float4 o1 = *(const float4*)(dst + 4);
        *(float4*)dst = make_float4(o0.x + res[i][0], o0.y + res[i][1],
                                    o0.z + res[i][2], o0.w + res[i][3]);
        *(float4*)(dst + 4) = make_float4(o1.x + res[i][4], o1.y + res[i][5],
                                          o1.z + res[i][6], o1.w + res[i][7]);
    }
}

// ---------------------------------------------------------------------------
// launch
// ---------------------------------------------------------------------------
extern "C" void kernel_launch(void* const* d_in, const int* in_sizes, int n_in,
                              void* d_out, int out_size, void* d_ws, size_t ws_size,
                              hipStream_t stream)
{
    (void)in_sizes; (void)n_in; (void)out_size; (void)ws_size;
    const float* q  = (const float*)d_in[0];
    const float* k  = (const float*)d_in[1];
    const float* v  = (const float*)d_in[2];
    const float* cw = (const float*)d_in[3];
    float* out = (float*)d_out;
    float* ws  = (float*)d_ws;

    const size_t LM = (size_t)LM_E;   // 262144 floats
    const size_t MM = (size_t)MM_E;   // 1048576 floats

    // float-unit layout (~29.6 MB):
    float* ql  = ws;                  // LM
    float* kl  = ql  + LM;            // LM
    float* xsf = kl  + LM;            // MM floats = x planes (xh|xl)
    float* zf0 = xsf + MM;            // MM floats = z fp32 buffer 0
    float* big = zf0 + MM;            // 4MM floats: zf1 | y planes | y2 planes | w1 planes
    float* kvf = big + 4 * MM;        // LM floats = kv planes
    float* W   = kvf + LM;            // LM floats
    float* scl = W   + LM;            // 16
    float* pm  = scl + 16;
    float* pl  = pm + (size_t)NBH * NSPLIT3 * MLAND;

    float* pO  = big;                 // 2MM floats (zf1 + y region), dead before chain
    float* zf1 = big;                 // MM floats

    unsigned short* xs  = (unsigned short*)xsf;
    unsigned short* kvs = (unsigned short*)kvf;

    unsigned short* xh  = xs;
    unsigned short* xl  = xs + MM_E;
    unsigned short* yh  = (unsigned short*)(big + MM);
    unsigned short* yl  = yh + MM_E;
    unsigned short* y2h = (unsigned short*)(big + 2 * MM);
    unsigned short* y2l = y2h + MM_E;
    unsigned short* w1h = (unsigned short*)(big + 3 * MM);
    unsigned short* w1l = w1h + MM_E;
    unsigned short* kvh = kvs;
    unsigned short* kvl = kvs + LM_E;

    hipMemsetAsync(scl, 0, 32, stream);

    k_landmarks<<<dim3(NBH * MLAND, 2), 64, 0, stream>>>(q, k, ql, kl);
    k_sim2_softmax<<<NBH * MLAND, 256, 0, stream>>>(ql, kl, xs);
    k_scale_reduce<<<dim3(16, NBH), 256, 0, stream>>>(xs, scl);
    k_zinit<<<dim3(8, 8, NBH), 256, 0, stream>>>(xs, zf0, scl);

    k_attn3_partial<<<dim3(NSPLIT3, 4, NBH), 256, 0, stream>>>(ql, k, v, pO, pm, pl);
    k_attn3_combine<<<NBH * MLAND, 64, 0, stream>>>(pO, pm, pl, kvs);

    // Moore-Penrose: zn = 3.25 zc - 3.75 (zc y) + 1.75 (zc y^2) - 0.25 (zc y^3),
    // y = x @ zc. 3 launches per iteration.
    float* zc = zf0;
    float* zn = zf1;
    for (int it = 0; it < 6; ++it) {
        k_gemm_y<<<512, 256, 0, stream>>>(xh, xl, zc, yh, yl);
        k_gemm_l2<<<1024, 256, 0, stream>>>(yh, yl, zc, y2h, y2l, w1h, w1l, zn);
        k_gemm_l3<<<1024, 256, 0, stream>>>(zc, y2h, y2l, w1h, w1l, zn);
        float* tt = zc; zc = zn; zn = tt;
    }
    // W = zfinal @ kv  [256x256 @ 256x64]
    k_gemm_w<<<128, 256, 0, stream>>>(zc, kvh, kvl, W);

    k_attn1_mfma<<<dim3(128, NBH), 256, 0, stream>>>(q, kl, W, out);
    k_conv_add<<<dim3(64, NBH), 256, 0, stream>>>(v, cw, out);
}